// Round 12
// baseline (1067.614 us; speedup 1.0000x reference)
//
#include <hip/hip_runtime.h>

#define NSRC 50000
#define NDST 50000
#define NE   1600000
#define DD   64
#define NEG  0.2f

typedef unsigned short ushort_t;
typedef __attribute__((ext_vector_type(8))) short short8;
typedef __attribute__((ext_vector_type(4))) float f32x4;
#define MFMA __builtin_amdgcn_mfma_f32_16x16x32_bf16

// ---------------- workspace layout (bytes) ----------------
#define OFF_FS      ((size_t)0)
#define OFF_FD      (OFF_FS     + (size_t)NSRC*DD*4)          // 12.8 MB
#define OFF_LOGITS  (OFF_FD     + (size_t)NDST*DD*4)          // +12.8 MB (CSR-sorted logits)
#define OFF_WLA     (OFF_LOGITS + (size_t)NE*4)               // +6.4 MB
#define OFF_CNT     (OFF_WLA    + 512)
#define OFF_CUR     (OFF_CNT    + (size_t)NDST*4 + 256)
#define OFF_ROWOFF  (OFF_CUR    + (size_t)NDST*4 + 256)
#define OFF_BSUM    (OFF_ROWOFF + (size_t)(NDST+1)*4 + 252)
#define OFF_BBASE   (OFF_BSUM   + 1024)
#define OFF_SSRC    (OFF_BBASE  + 1024)                        // +6.4 MB (CSR-sorted src ids)
#define OFF_INV     (OFF_SSRC   + (size_t)NE*4)                // +6.4 MB (edge -> CSR slot)
#define OFF_LMAX    (OFF_INV    + (size_t)NE*4)                // +200 KB (per-dst max key)
#define OFF_WT      ((OFF_LMAX + (size_t)NDST*4 + 255) & ~(size_t)255)  // 6 x 16KB packed W

__device__ __forceinline__ ushort_t rne16(float x) {           // fp32 -> bf16 RNE
    unsigned u = __float_as_uint(x);
    return (ushort_t)((u + 0x7fffu + ((u >> 16) & 1u)) >> 16);
}

// split fp32 -> bf16 hi (RNE) + bf16 lo (trunc of exact remainder)
__device__ __forceinline__ void bsplit(float x, ushort_t& h, ushort_t& l) {
    h = rne16(x);
    float hf = __uint_as_float(((unsigned)h) << 16);
    float lf = x - hf;                               // exact
    l = (ushort_t)(__float_as_uint(lf) >> 16);       // trunc
}

// order-preserving float<->uint key (key monotone in f; key=0 == -inf sentinel)
__device__ __forceinline__ unsigned fkey(float f) {
    unsigned u = __float_as_uint(f);
    return ((int)u >= 0) ? (u | 0x80000000u) : ~u;
}
__device__ __forceinline__ float funkey(unsigned k) {
    unsigned b = (k & 0x80000000u) ? (k & 0x7fffffffu) : ~k;
    return __uint_as_float(b);
}

// ---------------- K_PREP: W->bf16x2 planes, wla, cnt/lmax zero ----------------
__global__ __launch_bounds__(256) void k_prep(
    const float* __restrict__ We, const float* __restrict__ Wm1,
    const float* __restrict__ Wm2, const float* __restrict__ Wm3,
    const float* __restrict__ Wsrc, const float* __restrict__ Wdst,
    const float* __restrict__ Wel, const float* __restrict__ bel,
    const float* __restrict__ attn,
    ushort_t* __restrict__ wt, float* __restrict__ wla,
    int* __restrict__ cnt, unsigned* __restrict__ lmax)
{
    int b = blockIdx.x, t = threadIdx.x;
    if (b < 6) {
        const float* W = (b==0)?We:(b==1)?Wm1:(b==2)?Wm2:(b==3)?Wm3:(b==4)?Wsrc:Wdst;
        ushort_t* hi = wt + (size_t)b*8192;
        ushort_t* lo = hi + 4096;
        for (int j = t; j < 4096; j += 256) {
            int n = j >> 6, k = j & 63;
            ushort_t h, l; bsplit(W[k*64 + n], h, l);   // store transposed: [n][k]
            hi[j] = h; lo[j] = l;
        }
    } else if (b == 6) {
        if (t < DD) { float s = 0.f; for (int j = 0; j < DD; j++) s += Wel[t*DD+j]*attn[j]; wla[t] = s; }
        else if (t == DD) { float s = 0.f; for (int j = 0; j < DD; j++) s += bel[j]*attn[j]; wla[DD] = s; }
    } else {
        int gid = (b-7)*256 + t;
        if (gid < NDST) { cnt[gid] = 0; lmax[gid] = 0u; }
    }
}

// ---------------- K_NODEPROJ (MFMA, dual-plane X and W): fs/fd = feat @ W + b ----------------
__global__ __launch_bounds__(256, 3) void k_nodeproj(
    const float* __restrict__ feat_src, const float* __restrict__ feat_dst,
    const float* __restrict__ b_src, const float* __restrict__ b_dst,
    const ushort_t* __restrict__ wt,
    float* __restrict__ fs, float* __restrict__ fd)
{
    __shared__ ushort_t Xhi[64][72], Xlo[64][72], Whi[64][72], Wlo[64][72];
    __shared__ float bshs[64];
    int t = threadIdx.x, b = blockIdx.x;
    int which = (b >= 782);
    int rbase = (which ? b - 782 : b) * 64;
    const float* feat = which ? feat_dst : feat_src;
    const float* bias = which ? b_dst : b_src;
    float* outp = which ? fd : fs;
    const ushort_t* g = wt + (size_t)(4 + which) * 8192;

    if (t < 64) bshs[t] = bias[t];
    {   // stage feat tile -> bf16x2 planes
        int row = t >> 2, cs = (t & 3) * 16;
        int grow = rbase + row;
        const float4* src = (const float4*)(feat + (size_t)grow*DD + cs);
#pragma unroll
        for (int q = 0; q < 4; q++) {
            float4 v = (grow < NSRC) ? src[q] : make_float4(0.f,0.f,0.f,0.f);
#pragma unroll
            for (int j = 0; j < 4; j++) {
                float x = (j==0)?v.x:(j==1)?v.y:(j==2)?v.z:v.w;
                ushort_t h, l; bsplit(x, h, l);
                Xhi[row][cs+q*4+j] = h; Xlo[row][cs+q*4+j] = l;
            }
        }
    }
    {   // stage W planes: 16 shorts (= 2 x uint4) per thread
        int n = t >> 2, ks = (t & 3) * 16;
        *(uint4*)&Whi[n][ks]   = *(const uint4*)&g[n*64 + ks];
        *(uint4*)&Whi[n][ks+8] = *(const uint4*)&g[n*64 + ks + 8];
        *(uint4*)&Wlo[n][ks]   = *(const uint4*)&g[4096 + n*64 + ks];
        *(uint4*)&Wlo[n][ks+8] = *(const uint4*)&g[4096 + n*64 + ks + 8];
    }
    __syncthreads();

    int wv = t >> 6, lane = t & 63;
    int mrow = 16*wv + (lane & 15);
    int abase = (lane >> 4) * 8;
    short8 ah0 = *(const short8*)&Xhi[mrow][abase];
    short8 ah1 = *(const short8*)&Xhi[mrow][32 + abase];
    short8 al0 = *(const short8*)&Xlo[mrow][abase];
    short8 al1 = *(const short8*)&Xlo[mrow][32 + abase];
#pragma unroll
    for (int tt = 0; tt < 4; tt++) {
        int n = (lane & 15) + 16*tt;
        short8 bh0 = *(const short8*)&Whi[n][abase];
        short8 bh1 = *(const short8*)&Whi[n][32 + abase];
        short8 bl0 = *(const short8*)&Wlo[n][abase];
        short8 bl1 = *(const short8*)&Wlo[n][32 + abase];
        f32x4 c = {0.f, 0.f, 0.f, 0.f};
        c = MFMA(ah0, bh0, c, 0,0,0); c = MFMA(ah1, bh1, c, 0,0,0);
        c = MFMA(ah0, bl0, c, 0,0,0); c = MFMA(ah1, bl1, c, 0,0,0);
        c = MFMA(al0, bh0, c, 0,0,0); c = MFMA(al1, bh1, c, 0,0,0);
#pragma unroll
        for (int r = 0; r < 4; r++) {
            int m = 16*wv + (lane >> 4)*4 + r;
            int grow = rbase + m;
            if (grow < NSRC) outp[(size_t)grow*DD + n] = c[r] + bshs[n];
        }
    }
}

// ---------------- K2: histogram of dst ----------------
__global__ void k_hist(const int* __restrict__ dst_idx, int* __restrict__ cnt) {
    int e = blockIdx.x*256 + threadIdx.x;
    if (e < NE) atomicAdd(&cnt[dst_idx[e]], 1);
}

// ---------------- scan (3 phases) ----------------
__global__ __launch_bounds__(1024) void k_scan_a(const int* __restrict__ cnt,
                                                 int* __restrict__ row_off,
                                                 int* __restrict__ bsum) {
    __shared__ int sm[1024];
    int t = threadIdx.x, b = blockIdx.x;
    int i = b*1024 + t;
    int v = (i < NDST) ? cnt[i] : 0;
    sm[t] = v;
    __syncthreads();
    for (int o = 1; o < 1024; o <<= 1) {
        int add = (t >= o) ? sm[t-o] : 0;
        __syncthreads();
        sm[t] += add;
        __syncthreads();
    }
    if (i < NDST) row_off[i+1] = sm[t];
    if (t == 1023) bsum[b] = sm[t];
}

__global__ void k_scan_b(const int* __restrict__ bsum, int* __restrict__ bbase,
                         int* __restrict__ row_off, int nb) {
    if (threadIdx.x == 0 && blockIdx.x == 0) {
        int run = 0;
        for (int b = 0; b < nb; b++) { bbase[b] = run; run += bsum[b]; }
        row_off[0] = 0;
    }
}

__global__ __launch_bounds__(1024) void k_scan_c(const int* __restrict__ cnt,
                                                 const int* __restrict__ bbase,
                                                 int* __restrict__ row_off,
                                                 int* __restrict__ cur) {
    int t = threadIdx.x, b = blockIdx.x;
    int i = b*1024 + t;
    if (i < NDST) {
        int v = row_off[i+1] + bbase[b];
        row_off[i+1] = v;
        cur[i] = v - cnt[i];
    }
}

// ---------------- scatter into CSR: sorted src ids + inverse slot map ----------------
__global__ void k_scatter(const int* __restrict__ dst_idx, const int* __restrict__ src_idx,
                          int* __restrict__ cur,
                          int* __restrict__ ssrc, int* __restrict__ inv) {
    int e = blockIdx.x*256 + threadIdx.x;
    if (e < NE) {
        int p = atomicAdd(&cur[dst_idx[e]], 1);
        ssrc[p] = src_idx[e];
        inv[e] = p;
    }
}

// ---------------- K_EDGE v6: stage-pair-resident W, 3 barriers, fused max + sorted write ----
__global__ __launch_bounds__(256, 3) void k_edge(
    const float* __restrict__ e_feat, const ushort_t* __restrict__ wt,
    const float* __restrict__ b_e,  const float* __restrict__ b_m1,
    const float* __restrict__ b_m2, const float* __restrict__ b_m3,
    const int* __restrict__ src_idx, const int* __restrict__ dst_idx,
    const int* __restrict__ inv,
    const float* __restrict__ fs, const float* __restrict__ fd,
    const float* __restrict__ wla,
    float* __restrict__ logits_s, unsigned* __restrict__ lmax)
{
    __shared__ ushort_t Xhi[64][72];
    __shared__ ushort_t Whi[2][64][72], Wlo[2][64][72];   // two resident stages
    __shared__ float bshs[5*64 + 2];

    int t = threadIdx.x;
    int ebase = blockIdx.x * 64;
    int wv = t >> 6, lane = t & 63;
    int g = lane >> 4;
    int mrow = 16*wv + (lane & 15);
    int abase = g * 8;

    if (t < 64) {
        bshs[t]       = b_e[t];
        bshs[64+t]    = b_m1[t];
        bshs[128+t]   = b_m2[t];
        bshs[192+t]   = b_m3[t];
        bshs[256+t]   = wla[t];
    }
    if (t == 64) bshs[320] = wla[DD];

    // this wave's edge ids
    int se[4], de[4];
#pragma unroll
    for (int r = 0; r < 4; r++) {
        int eidx = ebase + 16*wv + g*4 + r;
        se[r] = src_idx[eidx];
        de[r] = dst_idx[eidx];
    }

    // stage-0 A-fragments straight from global
    short8 ah0, ah1;
    {
        const float* ef = e_feat + (size_t)(ebase + mrow)*DD;
        float4 u0 = *(const float4*)(ef + abase);
        float4 u1 = *(const float4*)(ef + abase + 4);
        float4 u2 = *(const float4*)(ef + 32 + abase);
        float4 u3 = *(const float4*)(ef + 32 + abase + 4);
        ah0[0]=(short)rne16(u0.x); ah0[1]=(short)rne16(u0.y); ah0[2]=(short)rne16(u0.z); ah0[3]=(short)rne16(u0.w);
        ah0[4]=(short)rne16(u1.x); ah0[5]=(short)rne16(u1.y); ah0[6]=(short)rne16(u1.z); ah0[7]=(short)rne16(u1.w);
        ah1[0]=(short)rne16(u2.x); ah1[1]=(short)rne16(u2.y); ah1[2]=(short)rne16(u2.z); ah1[3]=(short)rne16(u2.w);
        ah1[4]=(short)rne16(u3.x); ah1[5]=(short)rne16(u3.y); ah1[6]=(short)rne16(u3.z); ah1[7]=(short)rne16(u3.w);
    }

    // stage W pair 0 (stages 0,1), both planes
    {
        int n = t >> 2, ks = (t & 3) * 16;
#pragma unroll
        for (int sl = 0; sl < 2; sl++) {
            const ushort_t* wg = wt + (size_t)sl * 8192;
            *(uint4*)&Whi[sl][n][ks]   = *(const uint4*)&wg[n*64 + ks];
            *(uint4*)&Whi[sl][n][ks+8] = *(const uint4*)&wg[n*64 + ks + 8];
            *(uint4*)&Wlo[sl][n][ks]   = *(const uint4*)&wg[4096 + n*64 + ks];
            *(uint4*)&Wlo[sl][n][ks+8] = *(const uint4*)&wg[4096 + n*64 + ks + 8];
        }
    }
    __syncthreads();

    float lg[4] = {0.f, 0.f, 0.f, 0.f};

#pragma unroll
    for (int s = 0; s < 4; s++) {
        if (s == 2) {   // swap in W pair 1 (stages 2,3)
            __syncthreads();   // all waves done reading pair 0
            int n = t >> 2, ks = (t & 3) * 16;
#pragma unroll
            for (int sl = 0; sl < 2; sl++) {
                const ushort_t* wg = wt + (size_t)(2 + sl) * 8192;
                *(uint4*)&Whi[sl][n][ks]   = *(const uint4*)&wg[n*64 + ks];
                *(uint4*)&Whi[sl][n][ks+8] = *(const uint4*)&wg[n*64 + ks + 8];
                *(uint4*)&Wlo[sl][n][ks]   = *(const uint4*)&wg[4096 + n*64 + ks];
                *(uint4*)&Wlo[sl][n][ks+8] = *(const uint4*)&wg[4096 + n*64 + ks + 8];
            }
            __syncthreads();
        }
        int sl = s & 1;

        if (s > 0) {   // A-frags from LDS (this wave's previous epilogue; wave-private rows)
            ah0 = *(const short8*)&Xhi[mrow][abase];
            ah1 = *(const short8*)&Xhi[mrow][32 + abase];
        }

#pragma unroll
        for (int tt = 0; tt < 4; tt++) {
            int n = (lane & 15) + 16*tt;
            short8 bh0 = *(const short8*)&Whi[sl][n][abase];
            short8 bh1 = *(const short8*)&Whi[sl][n][32 + abase];
            short8 bl0 = *(const short8*)&Wlo[sl][n][abase];
            short8 bl1 = *(const short8*)&Wlo[sl][n][32 + abase];
            f32x4 c = {0.f, 0.f, 0.f, 0.f};
            c = MFMA(ah0, bh0, c, 0,0,0); c = MFMA(ah1, bh1, c, 0,0,0);
            c = MFMA(ah0, bl0, c, 0,0,0); c = MFMA(ah1, bl1, c, 0,0,0);
#pragma unroll
            for (int r = 0; r < 4; r++) {
                int m = 16*wv + g*4 + r;
                float val = c[r];
                if (s == 0)      val += bshs[n]     + fs[(size_t)se[r]*DD + n];
                else if (s == 1) val += bshs[64+n];
                else if (s == 2) val += bshs[128+n];
                else             val += bshs[192+n] + fd[(size_t)de[r]*DD + n];
                if (s < 3) {
                    float xn = fmaxf(val, NEG*val);     // lrelu -> next stage input
                    Xhi[m][n] = rne16(xn);
                } else {
                    float y = fmaxf(val, NEG*val);
                    lg[r] += y * bshs[256+n];
                }
            }
        }
        __builtin_amdgcn_wave_barrier();   // order X writes before next stage's reads
    }

#pragma unroll
    for (int r = 0; r < 4; r++) {
#pragma unroll
        for (int off = 1; off < 16; off <<= 1)
            lg[r] += __shfl_xor(lg[r], off, 64);
        if ((lane & 15) == 0) {
            int eidx = ebase + 16*wv + g*4 + r;
            float lf = lg[r] + bshs[320];
            logits_s[inv[eidx]] = lf;                       // CSR-sorted write
            atomicMax(&lmax[de[r]], fkey(lf));              // fused segment-max
        }
    }
}

// ---------------- K_AGG v3: streamed (coalesced) softmax + aggregation ----------------
__global__ __launch_bounds__(256) void k_agg(
    const int* __restrict__ row_off,
    const float* __restrict__ logits_s, const int* __restrict__ ssrc,
    const unsigned* __restrict__ lmax,
    const float* __restrict__ fs, float* __restrict__ out)
{
    __shared__ float psh[4][64];
    __shared__ int   ssh[4][64];
    int w = threadIdx.x >> 6, lane = threadIdx.x & 63;
    int d = blockIdx.x*4 + w;
    if (d >= NDST) return;
    int off = row_off[d], end = row_off[d+1];
    int deg = end - off;
    if (deg == 0) { out[(size_t)d*DD + lane] = 0.f; return; }

    float m = funkey(lmax[d]);   // precomputed segment max (scalar broadcast load)

    float ssum = 0.f, acc = 0.f;
    for (int base = 0; base < deg; base += 64) {
        int i = base + lane;
        float p = 0.f; int sj = 0;
        if (i < deg) {
            p  = __expf(logits_s[off+i] - m);   // coalesced stream
            sj = ssrc[off+i];                   // coalesced stream
        }
        ssum += p;
        psh[w][lane] = p;
        ssh[w][lane] = sj;
        __builtin_amdgcn_wave_barrier();
        int n = (deg - base < 64) ? (deg - base) : 64;
        for (int j = 0; j < n; j++) {
            float pj = psh[w][j];
            int   s2 = ssh[w][j];
            acc += pj * fs[(size_t)s2*DD + lane];
        }
        __builtin_amdgcn_wave_barrier();
    }
#pragma unroll
    for (int s = 32; s >= 1; s >>= 1)
        ssum += __shfl_xor(ssum, s, 64);

    out[(size_t)d*DD + lane] = acc / ssum;
}

// ---------------- launch ----------------
extern "C" void kernel_launch(void* const* d_in, const int* in_sizes, int n_in,
                              void* d_out, int out_size, void* d_ws, size_t ws_size,
                              hipStream_t stream)
{
    const float* feat_src = (const float*)d_in[0];
    const float* feat_dst = (const float*)d_in[1];
    const float* e_feat   = (const float*)d_in[2];
    const float* W_src = (const float*)d_in[3];
    const float* b_src = (const float*)d_in[4];
    const float* W_dst = (const float*)d_in[5];
    const float* b_dst = (const float*)d_in[6];
    const float* W_e   = (const float*)d_in[7];
    const float* b_e   = (const float*)d_in[8];
    const float* W_m1  = (const float*)d_in[9];
    const float* b_m1  = (const float*)d_in[10];
    const float* W_m2  = (const float*)d_in[11];
    const float* b_m2  = (const float*)d_in[12];
    const float* W_m3  = (const float*)d_in[13];
    const float* b_m3  = (const float*)d_in[14];
    const float* W_el  = (const float*)d_in[15];
    const float* b_el  = (const float*)d_in[16];
    const float* attn  = (const float*)d_in[17];
    const int* src_idx = (const int*)d_in[18];
    const int* dst_idx = (const int*)d_in[19];
    float* out = (float*)d_out;

    char* ws = (char*)d_ws;
    float* fs       = (float*)(ws + OFF_FS);
    float* fd       = (float*)(ws + OFF_FD);
    float* logits_s = (float*)(ws + OFF_LOGITS);
    float* wla      = (float*)(ws + OFF_WLA);
    int*   cnt      = (int*)  (ws + OFF_CNT);
    int*   cur      = (int*)  (ws + OFF_CUR);
    int*   row_off  = (int*)  (ws + OFF_ROWOFF);
    int*   bsum     = (int*)  (ws + OFF_BSUM);
    int*   bbase    = (int*)  (ws + OFF_BBASE);
    int*   ssrc     = (int*)  (ws + OFF_SSRC);
    int*   inv      = (int*)  (ws + OFF_INV);
    unsigned* lmax  = (unsigned*)(ws + OFF_LMAX);
    ushort_t* wt    = (ushort_t*)(ws + OFF_WT);

    const int NB_E256 = (NE + 255) / 256;            // 6250
    const int NB_SCAN = (NDST + 1023) / 1024;        // 49
    const int NB_PREP = 7 + (NDST + 255) / 256;      // 7 + 196

    k_prep<<<NB_PREP, 256, 0, stream>>>(W_e, W_m1, W_m2, W_m3, W_src, W_dst,
                                        W_el, b_el, attn, wt, wla, cnt, lmax);
    k_nodeproj<<<1564, 256, 0, stream>>>(feat_src, feat_dst, b_src, b_dst, wt, fs, fd);
    k_hist<<<NB_E256, 256, 0, stream>>>(dst_idx, cnt);
    k_scan_a<<<NB_SCAN, 1024, 0, stream>>>(cnt, row_off, bsum);
    k_scan_b<<<1, 64, 0, stream>>>(bsum, bbase, row_off, NB_SCAN);
    k_scan_c<<<NB_SCAN, 1024, 0, stream>>>(cnt, bbase, row_off, cur);
    k_scatter<<<NB_E256, 256, 0, stream>>>(dst_idx, src_idx, cur, ssrc, inv);
    k_edge<<<NE/64, 256, 0, stream>>>(e_feat, wt, b_e, b_m1, b_m2, b_m3,
                                      src_idx, dst_idx, inv, fs, fd, wla,
                                      logits_s, lmax);
    k_agg<<<(NDST + 3) / 4, 256, 0, stream>>>(row_off, logits_s, ssrc, lmax, fs, out);
}